// Round 16
// baseline (234.347 us; speedup 1.0000x reference)
//
#include <hip/hip_runtime.h>
#include <hip/hip_bf16.h>

typedef __attribute__((ext_vector_type(8))) short short8;
typedef __attribute__((ext_vector_type(4))) short short4v;
typedef __attribute__((ext_vector_type(4))) float f32x4;

#define MFMA16(a, b, c) __builtin_amdgcn_mfma_f32_16x16x32_bf16(a, b, c, 0, 0, 0)

__device__ __forceinline__ unsigned short f2bf(float f) {
    unsigned int u = __float_as_uint(f);
    unsigned int r = u + 0x7fffu + ((u >> 16) & 1u);
    return (unsigned short)(r >> 16);
}
__device__ __forceinline__ float bf2f(unsigned short h) {
    return __uint_as_float(((unsigned int)h) << 16);
}
__device__ __forceinline__ unsigned int pk2(float lo, float hi) {
    return (unsigned int)f2bf(lo) | ((unsigned int)f2bf(hi) << 16);
}
__device__ __forceinline__ unsigned int cvtpk(float lo, float hi) {
    unsigned int r;
    asm("v_cvt_pk_bf16_f32 %0, %1, %2" : "=v"(r) : "v"(lo), "v"(hi));
    return r;
}

__device__ __forceinline__ void async16(const void* g, void* l) {
    __builtin_amdgcn_global_load_lds(
        (const __attribute__((address_space(1))) unsigned int*)g,
        (__attribute__((address_space(3))) unsigned int*)l, 16, 0, 0);
}

#define S_BARRIER() asm volatile("s_barrier" ::: "memory")
#define SCHED_FENCE() __builtin_amdgcn_sched_barrier(0)

// ---------------- fp32 -> bf16 conversion for the 4 weight matrices (one launch) ------
__global__ __launch_bounds__(256) void cvt4_kernel(const float* __restrict__ w0,
                                                   const float* __restrict__ w1,
                                                   const float* __restrict__ w2,
                                                   const float* __restrict__ w3,
                                                   unsigned short* __restrict__ o0,
                                                   unsigned short* __restrict__ o1,
                                                   unsigned short* __restrict__ o2,
                                                   unsigned short* __restrict__ o3) {
    int wsel = blockIdx.x >> 7;
    int lb = blockIdx.x & 127;
    const float* in = wsel == 0 ? w0 : wsel == 1 ? w1 : wsel == 2 ? w2 : w3;
    unsigned short* out = wsel == 0 ? o0 : wsel == 1 ? o1 : wsel == 2 ? o2 : o3;
    for (int i = lb * 256 + threadIdx.x; i < 131072; i += 32768) {
        float4 v0 = reinterpret_cast<const float4*>(in)[2 * i];
        float4 v1 = reinterpret_cast<const float4*>(in)[2 * i + 1];
        uint4 p;
        p.x = pk2(v0.x, v0.y); p.y = pk2(v0.z, v0.w);
        p.z = pk2(v1.x, v1.y); p.w = pk2(v1.z, v1.w);
        reinterpret_cast<uint4*>(out)[i] = p;
    }
}

// ========== fp32-A GEMM (projections): C[M,1024] = A_f32 @ B_bf16^T + bias ==========
// R16: BM=BN=256, BK=32, 8 waves as 4M x 2N (wave 64 rows x 128 cols, acc[4][8]).
// A staged FP32 via async16 (no cvt pass), cvt to bf16 in-register post-ds_read.
// B read ONCE per kt and HELD (8 short8, R9's held-operand pattern) -> per kt reads:
// P1 = 8 B + 4 A = 12 b128, P2 = 4 A (near read-free) vs 32 MFMA -- balanced, vs
// R15's 20 reads per 32 MFMA (LDS-read-bound). Staging/gates identical to R15:
// 3 buffers x (A 32KB + B 16KB) = 144KB, vmcnt(6) counted gate, XOR swizzles verified.
// mode 0: elu+1, bf16 out, normal layout        -- LDS-staged coalesced stores
// mode 1: elu+1, bf16 out, transposed [n*1024+col][4096]
// mode 2: plain, bf16 out, transposed
__device__ __forceinline__ void gemm_f32a(const float* __restrict__ A,
                                          const unsigned short* __restrict__ B,
                                          const float* __restrict__ bias,
                                          void* __restrict__ out,
                                          int mode, char* lds, int bid) {
    const int tid = threadIdx.x;             // 0..511
    const int lane = tid & 63, wid = tid >> 6;
    const int wr = wid >> 1, wc = wid & 1;   // wave out: rows wr*64, cols wc*128
    const int lr = lane & 15, lg = lane >> 4;

    const int swz = (bid & 7) * 32 + (bid >> 3);
    const int bm = swz >> 2, bn = swz & 3;
    const long row0 = (long)bm * 256;
    const long col0 = (long)bn * 256;

    // ---- staging sources (pre-swizzled; LDS dest linear) ----
    // A region/buffer: 256 rows x 8 chunks (16B = 4 f32). chunk s: pr=s>>3, dc=(s&7)^(pr&7)
    const float* srcA[4];
#pragma unroll
    for (int g = 0; g < 4; ++g) {
        int s = g * 512 + tid;
        int pr = s >> 3;
        int dc = (s & 7) ^ (pr & 7);
        srcA[g] = A + (row0 + pr) * 1024 + dc * 4;
    }
    // B region/buffer: 128 phys rows (pairing cols c and c+128) x 8 chunks (16B = 8 bf16)
    const unsigned short* srcB[2];
#pragma unroll
    for (int g = 0; g < 2; ++g) {
        int s = g * 512 + tid;
        int pr = s >> 3;
        int dc = (s & 7) ^ (pr & 7);
        srcB[g] = B + (col0 + pr + 128 * (dc >> 2)) * 1024 + (dc & 3) * 8;
    }
    const int dst = tid * 16;

#define STAGE_A(BUF, KT) do {                                                   \
        async16(srcA[0] + (KT) * 32, (BUF) + dst);                              \
        async16(srcA[1] + (KT) * 32, (BUF) + 8192 + dst);                       \
        async16(srcA[2] + (KT) * 32, (BUF) + 16384 + dst);                      \
        async16(srcA[3] + (KT) * 32, (BUF) + 24576 + dst); } while (0)
#define STAGE_B(BUF, KT) do {                                                   \
        async16(srcB[0] + (KT) * 32, (BUF) + 32768 + dst);                      \
        async16(srcB[1] + (KT) * 32, (BUF) + 40960 + dst); } while (0)

    // ---- ds_read byte offsets ----
    // A frag m (0..3): row = wr*64 + m*16 + lr (128B rows); chunks {2lg, 2lg+1} ^ (lr&7)
    int offA[4];
#pragma unroll
    for (int m = 0; m < 4; ++m)
        offA[m] = (wr * 64 + m * 16 + lr) * 128 + (((2 * lg) ^ (lr & 7)) << 4);
    // B frag n (0..7): phys row n*16 + lr; data chunk wc*4 + lg
    int offB[8];
#pragma unroll
    for (int n = 0; n < 8; ++n)
        offB[n] = 32768 + (n * 16 + lr) * 128 + (((wc * 4 + lg) ^ (lr & 7)) << 4);

    f32x4 acc[4][8] = {};

    char* p0 = lds;            // kt   (read)
    char* p1 = lds + 49152;    // kt+1 (landed-or-inflight)
    char* p2 = lds + 98304;    // kt+2 (stage target)

    // prologue: stage kt0, kt1; wait kt0 (kt1's 6 stay outstanding)
    STAGE_A(p0, 0); STAGE_B(p0, 0);
    STAGE_A(p1, 1); STAGE_B(p1, 1);
    asm volatile("s_waitcnt vmcnt(6)" ::: "memory");
    SCHED_FENCE();
    S_BARRIER();

#pragma unroll 1
    for (int kt = 0; kt < 32; ++kt) {
        short8 bfr[8];   // held across both phases
        { // P1: B all + A m0-1 ; stage A(kt+2)
            float4 a0[2], a1[2];
#pragma unroll
            for (int n = 0; n < 8; ++n) bfr[n] = *(const short8*)(p0 + offB[n]);
#pragma unroll
            for (int m = 0; m < 2; ++m) {
                a0[m] = *(const float4*)(p0 + offA[m]);
                a1[m] = *(const float4*)(p0 + (offA[m] ^ 16));
            }
            SCHED_FENCE();
            if (kt < 30) STAGE_A(p2, kt + 2);
            asm volatile("s_waitcnt lgkmcnt(0)" ::: "memory");
            SCHED_FENCE();
            short8 af[2];
#pragma unroll
            for (int m = 0; m < 2; ++m) {
                union { unsigned int u[4]; short8 s; } cv;
                cv.u[0] = cvtpk(a0[m].x, a0[m].y);
                cv.u[1] = cvtpk(a0[m].z, a0[m].w);
                cv.u[2] = cvtpk(a1[m].x, a1[m].y);
                cv.u[3] = cvtpk(a1[m].z, a1[m].w);
                af[m] = cv.s;
            }
            __builtin_amdgcn_s_setprio(1);
#pragma unroll
            for (int m = 0; m < 2; ++m)
#pragma unroll
                for (int n = 0; n < 8; ++n)
                    acc[m][n] = MFMA16(af[m], bfr[n], acc[m][n]);
            __builtin_amdgcn_s_setprio(0);
            SCHED_FENCE();
            S_BARRIER();
        }
        { // P2: A m2-3 ; stage B(kt+2) ; gate
            float4 a0[2], a1[2];
#pragma unroll
            for (int m = 0; m < 2; ++m) {
                a0[m] = *(const float4*)(p0 + offA[2 + m]);
                a1[m] = *(const float4*)(p0 + (offA[2 + m] ^ 16));
            }
            SCHED_FENCE();
            if (kt < 30) STAGE_B(p2, kt + 2);
            if (kt < 30) {
                asm volatile("s_waitcnt vmcnt(6)" ::: "memory");  // kt+1 resident
            } else {
                asm volatile("s_waitcnt vmcnt(0)" ::: "memory");  // tail (loads old)
            }
            SCHED_FENCE();
            asm volatile("s_waitcnt lgkmcnt(0)" ::: "memory");
            SCHED_FENCE();
            short8 af[2];
#pragma unroll
            for (int m = 0; m < 2; ++m) {
                union { unsigned int u[4]; short8 s; } cv;
                cv.u[0] = cvtpk(a0[m].x, a0[m].y);
                cv.u[1] = cvtpk(a0[m].z, a0[m].w);
                cv.u[2] = cvtpk(a1[m].x, a1[m].y);
                cv.u[3] = cvtpk(a1[m].z, a1[m].w);
                af[m] = cv.s;
            }
            __builtin_amdgcn_s_setprio(1);
#pragma unroll
            for (int m = 0; m < 2; ++m)
#pragma unroll
                for (int n = 0; n < 8; ++n)
                    acc[2 + m][n] = MFMA16(af[m], bfr[n], acc[2 + m][n]);
            __builtin_amdgcn_s_setprio(0);
            SCHED_FENCE();
            S_BARRIER();
        }
        char* t_ = p0; p0 = p1; p1 = p2; p2 = t_;
    }
#undef STAGE_A
#undef STAGE_B

    // ---- epilogue: wave tile 64 rows x 128 cols ----
    // row = row0 + wr*64 + m*16 + lg*4 + j ; col = col0 + wc*128 + n*16 + lr
    if (mode == 0) {
        // per-wave LDS staging [16 rows][128 cols] f32, stride 132 words; coalesced stores
        char* ep = lds + wid * 8448;
#pragma unroll
        for (int m = 0; m < 4; ++m) {
#pragma unroll
            for (int n = 0; n < 8; ++n) {
                float bcol = bias[col0 + wc * 128 + n * 16 + lr];
#pragma unroll
                for (int j = 0; j < 4; ++j) {
                    float v = acc[m][n][j] + bcol;
                    v = v > 0.f ? v + 1.f : __expf(v);
                    *(float*)(ep + (((lg * 4 + j) * 132) + n * 16 + lr) * 4) = v;
                }
            }
            asm volatile("s_waitcnt lgkmcnt(0)" ::: "memory");
            SCHED_FENCE();
            long R0b = row0 + wr * 64 + m * 16;
            unsigned short* O = (unsigned short*)out;
#pragma unroll
            for (int i = 0; i < 4; ++i) {
                int r = i * 4 + (lane >> 4), c8 = (lane & 15) * 8;
                float4 u0 = *(const float4*)(ep + (r * 132 + c8) * 4);
                float4 u1 = *(const float4*)(ep + (r * 132 + c8 + 4) * 4);
                uint4 w;
                w.x = pk2(u0.x, u0.y); w.y = pk2(u0.z, u0.w);
                w.z = pk2(u1.x, u1.y); w.w = pk2(u1.z, u1.w);
                *(uint4*)(O + (R0b + r) * 1024 + col0 + wc * 128 + c8) = w;
            }
            asm volatile("s_waitcnt lgkmcnt(0)" ::: "memory");
            SCHED_FENCE();
        }
    } else {
        const int r4 = lg * 4;
#pragma unroll
        for (int m = 0; m < 4; ++m) {
#pragma unroll
            for (int n = 0; n < 8; ++n) {
                long col = col0 + wc * 128 + n * 16 + lr;
                float bcol = bias[col];
                long R0 = row0 + wr * 64 + m * 16 + r4;
                unsigned short* O = (unsigned short*)out;
                long nb = R0 >> 12;
                long s = R0 & 4095;
                short4v pack;
#pragma unroll
                for (int j = 0; j < 4; ++j) {
                    float v = acc[m][n][j] + bcol;
                    if (mode == 1) v = v > 0.f ? v + 1.f : __expf(v);
                    pack[j] = (short)f2bf(v);
                }
                *(short4v*)(O + ((nb << 10) + col) * 4096 + s) = pack;
            }
        }
    }
}

// ========== bf16 GEMM body (R9-verified, for output projection) ==========
__device__ __forceinline__ void gemm_body(const unsigned short* __restrict__ A,
                                          const unsigned short* __restrict__ B,
                                          const float* __restrict__ bias,
                                          float* __restrict__ out,
                                          char* lds, int bid) {
    const int tid = threadIdx.x;
    const int lane = tid & 63, wid = tid >> 6;
    const int wr = wid >> 2, wc = wid & 3;
    const int lr = lane & 15, lg = lane >> 4;

    const int swz = (bid & 7) * 32 + (bid >> 3);
    const int bm = swz >> 2, bn = swz & 3;
    const long row0 = (long)bm * 256;
    const long col0 = (long)bn * 256;

    const unsigned short* srcA[2];
    const unsigned short* srcB[2];
    int dstOff[2];
#pragma unroll
    for (int g = 0; g < 2; ++g) {
        int s = g * 512 + tid;
        int pr = s >> 3;
        int dc = (s & 7) ^ (pr & 7);
        srcA[g] = A + (row0 + (pr & 63) + 128 * (pr >> 6)) * 1024 + dc * 8;
        srcB[g] = B + (col0 + pr) * 1024 + dc * 8;
        dstOff[g] = s * 16;
    }

#define STG_AQ(BB, Q, KT) do {                                                  \
        async16(srcA[0] + (Q) * 65536 + (KT) * 64,                              \
                lds + (BB) * 65536 + (Q) * 16384 + dstOff[0]);                  \
        async16(srcA[1] + (Q) * 65536 + (KT) * 64,                              \
                lds + (BB) * 65536 + (Q) * 16384 + dstOff[1]); } while (0)
#define STG_BH(BB, H, KT) do {                                                  \
        async16(srcB[0] + (H) * 131072 + (KT) * 64,                             \
                lds + (BB) * 65536 + 32768 + (H) * 16384 + dstOff[0]);          \
        async16(srcB[1] + (H) * 131072 + (KT) * 64,                             \
                lds + (BB) * 65536 + 32768 + (H) * 16384 + dstOff[1]); } while (0)

    const int ch0 = ((lg ^ (lr & 7)) << 4);
    const int ch1 = (((4 + lg) ^ (lr & 7)) << 4);
    const int aB0 = (64 * wr + lr) * 128 + ch0;
    const int aB1 = (64 * wr + lr) * 128 + ch1;
    const int bB0 = 32768 + (wc >> 1) * 16384 + ((wc & 1) * 64 + lr) * 128 + ch0;
    const int bB1 = 32768 + (wc >> 1) * 16384 + ((wc & 1) * 64 + lr) * 128 + ch1;

    f32x4 acc[8][4] = {};
    short8 b0[4], b1[4];

#define GATE4() do { asm volatile("s_waitcnt vmcnt(4)" ::: "memory"); SCHED_FENCE(); } while (0)
#define GATE0() do { asm volatile("s_waitcnt vmcnt(0)" ::: "memory"); SCHED_FENCE(); } while (0)
#define MFMA_BLOCK(MB, BV) do {                                                 \
        S_BARRIER();                                                            \
        asm volatile("s_waitcnt lgkmcnt(0)" ::: "memory");                      \
        SCHED_FENCE();                                                          \
        __builtin_amdgcn_s_setprio(1);                                          \
        _Pragma("unroll") for (int m = 0; m < 4; ++m)                           \
            _Pragma("unroll") for (int n = 0; n < 4; ++n)                       \
                acc[(MB) + m][n] = MFMA16(a[m], BV[n], acc[(MB) + m][n]);       \
        __builtin_amdgcn_s_setprio(0);                                          \
        SCHED_FENCE();                                                          \
        S_BARRIER(); } while (0)
#define LOAD_A(BUFB, ABASE, Q) do {                                             \
        _Pragma("unroll") for (int m = 0; m < 4; ++m)                           \
            a[m] = *(const short8*)(lds + (BUFB) + (Q) * 16384 + (ABASE) + m * 2048); } while (0)
#define LOAD_B(BUFB, BBASE, BV) do {                                            \
        _Pragma("unroll") for (int n = 0; n < 4; ++n)                           \
            BV[n] = *(const short8*)(lds + (BUFB) + (BBASE) + n * 2048); } while (0)

    STG_AQ(0, 0, 0); STG_BH(0, 0, 0); STG_BH(0, 1, 0); STG_AQ(0, 1, 0);
    STG_AQ(1, 0, 1); STG_BH(1, 0, 1);
    GATE4();
    S_BARRIER();

#pragma unroll 1
    for (int t = 0; t < 7; ++t) {
        const int ktA = 2 * t + 1, ktB = 2 * t + 2, ktC = 2 * t + 3;
        { short8 a[4]; LOAD_B(0, bB0, b0); LOAD_A(0, aB0, 0); STG_BH(1, 1, ktA); MFMA_BLOCK(0, b0); }
        { short8 a[4]; LOAD_B(0, bB1, b1); LOAD_A(0, aB1, 0); STG_AQ(1, 1, ktA); MFMA_BLOCK(0, b1); }
        { short8 a[4]; LOAD_A(0, aB0, 1); STG_AQ(0, 0, ktB); MFMA_BLOCK(4, b0); }
        { short8 a[4]; LOAD_A(0, aB1, 1); STG_BH(0, 0, ktB); GATE4(); MFMA_BLOCK(4, b1); }
        { short8 a[4]; LOAD_B(65536, bB0, b0); LOAD_A(65536, aB0, 0); STG_BH(0, 1, ktB); MFMA_BLOCK(0, b0); }
        { short8 a[4]; LOAD_B(65536, bB1, b1); LOAD_A(65536, aB1, 0); STG_AQ(0, 1, ktB); MFMA_BLOCK(0, b1); }
        { short8 a[4]; LOAD_A(65536, aB0, 1); STG_AQ(1, 0, ktC); MFMA_BLOCK(4, b0); }
        { short8 a[4]; LOAD_A(65536, aB1, 1); STG_BH(1, 0, ktC); GATE4(); MFMA_BLOCK(4, b1); }
    }
    {
        { short8 a[4]; LOAD_B(0, bB0, b0); LOAD_A(0, aB0, 0); STG_BH(1, 1, 15); MFMA_BLOCK(0, b0); }
        { short8 a[4]; LOAD_B(0, bB1, b1); LOAD_A(0, aB1, 0); STG_AQ(1, 1, 15); MFMA_BLOCK(0, b1); }
        { short8 a[4]; LOAD_A(0, aB0, 1); MFMA_BLOCK(4, b0); }
        { short8 a[4]; LOAD_A(0, aB1, 1); GATE0(); MFMA_BLOCK(4, b1); }
        { short8 a[4]; LOAD_B(65536, bB0, b0); LOAD_A(65536, aB0, 0); MFMA_BLOCK(0, b0); }
        { short8 a[4]; LOAD_B(65536, bB1, b1); LOAD_A(65536, aB1, 0); MFMA_BLOCK(0, b1); }
        { short8 a[4]; LOAD_A(65536, aB0, 1); MFMA_BLOCK(4, b0); }
        { short8 a[4]; LOAD_A(65536, aB1, 1); MFMA_BLOCK(4, b1); }
    }
#undef STG_AQ
#undef STG_BH
#undef GATE4
#undef GATE0
#undef MFMA_BLOCK
#undef LOAD_A
#undef LOAD_B

    {
        char* ep = lds + wid * 4608;
#pragma unroll
        for (int m = 0; m < 8; ++m) {
#pragma unroll
            for (int n = 0; n < 4; ++n) {
                float bcol = bias[col0 + wc * 64 + n * 16 + lr];
#pragma unroll
                for (int j = 0; j < 4; ++j)
                    *(float*)(ep + (((lg * 4 + j) * 68) + n * 16 + lr) * 4) = acc[m][n][j] + bcol;
            }
            asm volatile("s_waitcnt lgkmcnt(0)" ::: "memory");
            SCHED_FENCE();
            long R0b = row0 + wr * 128 + m * 16;
#pragma unroll
            for (int i = 0; i < 4; ++i) {
                int r = i * 4 + (lane >> 4), c4 = (lane & 15) * 4;
                float4 u = *(const float4*)(ep + (r * 68 + c4) * 4);
                *(float4*)(out + (R0b + r) * 1024 + col0 + wc * 64 + c4) = u;
            }
            asm volatile("s_waitcnt lgkmcnt(0)" ::: "memory");
            SCHED_FENCE();
        }
    }
}

// ---- merged Q/K/V projection from FP32 inputs: 768 blocks ----
__global__ __launch_bounds__(512, 1) void proj_gemm(const float* __restrict__ q,
                                                    const float* __restrict__ k,
                                                    const float* __restrict__ v,
                                                    const unsigned short* __restrict__ Wqb,
                                                    const unsigned short* __restrict__ Wkb,
                                                    const unsigned short* __restrict__ Wvb,
                                                    const float* __restrict__ bq,
                                                    const float* __restrict__ bk,
                                                    const float* __restrict__ bv,
                                                    unsigned short* __restrict__ Qm,
                                                    unsigned short* __restrict__ Kt,
                                                    unsigned short* __restrict__ vT) {
    __shared__ __align__(16) char lds[147456];
    int seg = blockIdx.x >> 8;
    int bid = blockIdx.x & 255;
    const float* A = seg == 0 ? q : seg == 1 ? k : v;
    const unsigned short* B = seg == 0 ? Wqb : seg == 1 ? Wkb : Wvb;
    const float* bias = seg == 0 ? bq : seg == 1 ? bk : bv;
    void* out = seg == 0 ? (void*)Qm : seg == 1 ? (void*)Kt : (void*)vT;
    gemm_f32a(A, B, bias, out, seg, lds, bid);   // mode 0/1/2 == seg
}

// ---- output projection: 256 blocks, bf16 A (R9 body) ----
__global__ __launch_bounds__(512, 1) void out_gemm(const unsigned short* __restrict__ Vbuf,
                                                   const unsigned short* __restrict__ Wob,
                                                   const float* __restrict__ bo,
                                                   float* __restrict__ out) {
    __shared__ __align__(16) char lds[131072];
    gemm_body(Vbuf, Wob, bo, out, lds, blockIdx.x);
}

// ---------------- KV[n,h,m,d] = sum_s vT[...][s] * Kt[...][s]; Ksum fused from B-frags ----
__global__ __launch_bounds__(256) void kv_kernel(const unsigned short* __restrict__ Kt,
                                                 const unsigned short* __restrict__ vT,
                                                 float* __restrict__ KV,
                                                 float* __restrict__ Ksum) {
    int b = blockIdx.x;
    int sc = b & 7, h = (b >> 3) & 15, n = b >> 7;
    const int tid = threadIdx.x, lane = tid & 63, wave = tid >> 6;
    long base = ((long)(n * 1024 + h * 64)) * 4096 + sc * 512;
    const unsigned short* Kp = Kt + base;
    const unsigned short* Vp = vT + base;
    const int lr = lane & 15, lk = (lane >> 4) * 8;

    f32x4 acc[4] = {};
    float ksa[4] = {0.f, 0.f, 0.f, 0.f};
    for (int s0 = 0; s0 < 512; s0 += 32) {
        short8 a = *(const short8*)(Vp + (long)(wave * 16 + lr) * 4096 + s0 + lk);
#pragma unroll
        for (int d4 = 0; d4 < 4; ++d4) {
            short8 bb = *(const short8*)(Kp + (long)(d4 * 16 + lr) * 4096 + s0 + lk);
            acc[d4] = MFMA16(a, bb, acc[d4]);
            if (wave == 0) {
                float t = 0.f;
#pragma unroll
                for (int e = 0; e < 8; ++e) t += bf2f((unsigned short)bb[e]);
                ksa[d4] += t;
            }
        }
    }
    float* KVb = KV + (long)(n * 16 + h) * 4096;
#pragma unroll
    for (int d4 = 0; d4 < 4; ++d4)
#pragma unroll
        for (int j = 0; j < 4; ++j) {
            int m = wave * 16 + (lane >> 4) * 4 + j;
            int d = d4 * 16 + lr;
            atomicAdd(KVb + m * 64 + d, acc[d4][j]);
        }
    if (wave == 0) {
#pragma unroll
        for (int d4 = 0; d4 < 4; ++d4) {
            float t = ksa[d4];
            t += __shfl_xor(t, 16, 64);
            t += __shfl_xor(t, 32, 64);
            if (lane < 16) atomicAdd(Ksum + n * 1024 + h * 64 + d4 * 16 + lane, t);
        }
    }
}

// ---------------- attn: V[n,l,h,m] = (sum_d Q[l,d]*KV[m,d]) / (Q[l,:]·Ksum + eps) ----------------
__global__ __launch_bounds__(256) void attn_kernel(const unsigned short* __restrict__ Qm,
                                                   const float* __restrict__ KV,
                                                   const float* __restrict__ Ksum,
                                                   unsigned short* __restrict__ Vbuf) {
    __shared__ unsigned short Qs[128 * 64];
    __shared__ unsigned short KVs[64 * 64];
    __shared__ float zin[128];
    __shared__ float ks[64];
    int b = blockIdx.x;
    int lc = b & 31, h = (b >> 5) & 15, n = b >> 9;
    int tid = threadIdx.x, lane = tid & 63, wave = tid >> 6;
    long l0 = (long)n * 4096 + lc * 128;

    const unsigned short* Qg = Qm + (l0 + (tid >> 3)) * 1024 + h * 64 + (tid & 7) * 8;
    char* QsB = (char*)Qs + (wave << 10);
#pragma unroll
    for (int it = 0; it < 4; ++it)
        async16(Qg + (long)it * 32 * 1024, QsB + it * 4096);

    const float* kvp = KV + (long)(n * 16 + h) * 4096;
    for (int i = tid * 4; i < 4096; i += 1024) {
        float4 v = *reinterpret_cast<const float4*>(kvp + i);
        short4v p;
        p[0] = (short)f2bf(v.x); p[1] = (short)f2bf(v.y);
        p[2] = (short)f2bf(v.z); p[3] = (short)f2bf(v.w);
        *(short4v*)(KVs + i) = p;
    }
    if (tid < 64) ks[tid] = Ksum[n * 1024 + h * 64 + tid];
    __syncthreads();

    {
        int row = tid >> 1, half = tid & 1;
        float den = 0.f;
        const unsigned short* qrow = Qs + row * 64 + half * 32;
#pragma unroll
        for (int d = 0; d < 32; ++d) den += bf2f(qrow[d]) * ks[half * 32 + d];
        den += __shfl_xor(den, 1, 64);
        if (half == 0) zin[row] = 1.0f / (den + 1e-6f);
    }
    __syncthreads();

    const int lr = lane & 15, lk = (lane >> 4) * 8;
    f32x4 acc[2][4] = {};
#pragma unroll
    for (int kk = 0; kk < 2; ++kk) {
        short8 a0 = *(const short8*)(Qs + (wave * 32 + lr) * 64 + kk * 32 + lk);
        short8 a1 = *(const short8*)(Qs + (wave * 32 + 16 + lr) * 64 + kk * 32 + lk);
#pragma unroll
        for (int nn = 0; nn < 4; ++nn) {
            short8 bb = *(const short8*)(KVs + (nn * 16 + lr) * 64 + kk * 32 + lk);
            acc[0][nn] = MFMA16(a0, bb, acc[0][nn]);
            acc[1][nn] = MFMA16(a1, bb, acc[1][nn]);
        }
    }

    {
        char* ep = (char*)Qs + wave * 4096;
#pragma unroll
        for (int mi = 0; mi < 2; ++mi) {
#pragma unroll
            for (int nn = 0; nn < 4; ++nn)
#pragma unroll
                for (int j = 0; j < 4; ++j) {
                    int rloc = (lane >> 4) * 4 + j;
                    float v = acc[mi][nn][j] * zin[wave * 32 + mi * 16 + rloc];
                    *(float*)(ep + (rloc * 64 + nn * 16 + lr) * 4) = v;
                }
            asm volatile("s_waitcnt lgkmcnt(0)" ::: "memory");
            SCHED_FENCE();
#pragma unroll
            for (int i = 0; i < 2; ++i) {
                int r = i * 8 + (lane >> 3), c8 = (lane & 7) * 8;
                float4 u0 = *(const float4*)(ep + (r * 64 + c8) * 4);
                float4 u1 = *(const float4*)(ep + (r * 64 + c8 + 4) * 4);
                uint4 w;
                w.x = pk2(u0.x, u0.y); w.y = pk2(u0.z, u0.w);
                w.z = pk2(u1.x, u1.y); w.w = pk2(u1.z, u1.w);
                *(uint4*)(Vbuf + (l0 + wave * 32 + mi * 16 + r) * 1024 + h * 64 + c8) = w;
            }
            asm volatile("s_waitcnt lgkmcnt(0)" ::: "memory");
            SCHED_FENCE();
        }
    }
}

extern "C" void kernel_launch(void* const* d_in, const int* in_sizes, int n_in,
                              void* d_out, int out_size, void* d_ws, size_t ws_size,
                              hipStream_t stream) {
    const float* queries = (const float*)d_in[0];
    const float* keys    = (const float*)d_in[1];
    const float* values  = (const float*)d_in[2];
    const float* Wq = (const float*)d_in[3];
    const float* bq = (const float*)d_in[4];
    const float* Wk = (const float*)d_in[5];
    const float* bk = (const float*)d_in[6];
    const float* Wv = (const float*)d_in[7];
    const float* bv = (const float*)d_in[8];
    const float* Wo = (const float*)d_in[9];
    const float* bo = (const float*)d_in[10];
    float* out = (float*)d_out;

    char* ws = (char*)d_ws;
    const size_t SZ = (size_t)16384 * 1024 * 2;  // 33.5 MB bf16 matrix
    const size_t WSZ = (size_t)1024 * 1024 * 2;  // 2 MB bf16 weight
    unsigned short* Wqb = (unsigned short*)(ws);
    unsigned short* Wkb = (unsigned short*)(ws + WSZ);
    unsigned short* Wvb = (unsigned short*)(ws + 2 * WSZ);
    unsigned short* Wob = (unsigned short*)(ws + 3 * WSZ);
    unsigned short* Qm   = (unsigned short*)(ws + 4 * WSZ);
    unsigned short* Kt   = (unsigned short*)(ws + 4 * WSZ + SZ);
    unsigned short* vT   = (unsigned short*)(ws + 4 * WSZ + 2 * SZ);
    unsigned short* Vbuf = (unsigned short*)(ws + 4 * WSZ + 3 * SZ);
    float* KVf = (float*)(ws + 4 * WSZ + 4 * SZ);
    float* Ksf = (float*)(ws + 4 * WSZ + 4 * SZ + 1048576);

    hipMemsetAsync(KVf, 0, 1048576 + 16384, stream);

    cvt4_kernel<<<512, 256, 0, stream>>>(Wq, Wk, Wv, Wo, Wqb, Wkb, Wvb, Wob);

    proj_gemm<<<768, 512, 0, stream>>>(queries, keys, values, Wqb, Wkb, Wvb,
                                       bq, bk, bv, Qm, Kt, vT);

    kv_kernel<<<512, 256, 0, stream>>>(Kt, vT, KVf, Ksf);
    attn_kernel<<<2048, 256, 0, stream>>>(Qm, KVf, Ksf, Vbuf);

    out_gemm<<<256, 512, 0, stream>>>(Vbuf, Wob, bo, out);
}

// Round 17
// 232.877 us; speedup vs baseline: 1.0063x; 1.0063x over previous
//
#include <hip/hip_runtime.h>
#include <hip/hip_bf16.h>

typedef __attribute__((ext_vector_type(8))) short short8;
typedef __attribute__((ext_vector_type(4))) short short4v;
typedef __attribute__((ext_vector_type(4))) float f32x4;

#define MFMA16(a, b, c) __builtin_amdgcn_mfma_f32_16x16x32_bf16(a, b, c, 0, 0, 0)

__device__ __forceinline__ unsigned short f2bf(float f) {
    unsigned int u = __float_as_uint(f);
    unsigned int r = u + 0x7fffu + ((u >> 16) & 1u);
    return (unsigned short)(r >> 16);
}
__device__ __forceinline__ float bf2f(unsigned short h) {
    return __uint_as_float(((unsigned int)h) << 16);
}
__device__ __forceinline__ unsigned int pk2(float lo, float hi) {
    return (unsigned int)f2bf(lo) | ((unsigned int)f2bf(hi) << 16);
}
__device__ __forceinline__ unsigned int cvtpk(float lo, float hi) {
    unsigned int r;
    asm("v_cvt_pk_bf16_f32 %0, %1, %2" : "=v"(r) : "v"(lo), "v"(hi));
    return r;
}

__device__ __forceinline__ void async16(const void* g, void* l) {
    __builtin_amdgcn_global_load_lds(
        (const __attribute__((address_space(1))) unsigned int*)g,
        (__attribute__((address_space(3))) unsigned int*)l, 16, 0, 0);
}

#define S_BARRIER() asm volatile("s_barrier" ::: "memory")
#define SCHED_FENCE() __builtin_amdgcn_sched_barrier(0)

// ---------------- fp32 -> bf16 conversion for the 4 weight matrices (one launch) ------
__global__ __launch_bounds__(256) void cvt4_kernel(const float* __restrict__ w0,
                                                   const float* __restrict__ w1,
                                                   const float* __restrict__ w2,
                                                   const float* __restrict__ w3,
                                                   unsigned short* __restrict__ o0,
                                                   unsigned short* __restrict__ o1,
                                                   unsigned short* __restrict__ o2,
                                                   unsigned short* __restrict__ o3) {
    int wsel = blockIdx.x >> 7;
    int lb = blockIdx.x & 127;
    const float* in = wsel == 0 ? w0 : wsel == 1 ? w1 : wsel == 2 ? w2 : w3;
    unsigned short* out = wsel == 0 ? o0 : wsel == 1 ? o1 : wsel == 2 ? o2 : o3;
    for (int i = lb * 256 + threadIdx.x; i < 131072; i += 32768) {
        float4 v0 = reinterpret_cast<const float4*>(in)[2 * i];
        float4 v1 = reinterpret_cast<const float4*>(in)[2 * i + 1];
        uint4 p;
        p.x = pk2(v0.x, v0.y); p.y = pk2(v0.z, v0.w);
        p.z = pk2(v1.x, v1.y); p.w = pk2(v1.z, v1.w);
        reinterpret_cast<uint4*>(out)[i] = p;
    }
}

// ========== fp32-A GEMM (projections): C[M,1024] = A_f32 @ B_bf16^T + bias ==========
// R15 measured-best config. BM=BN=256, BK=32. 8 waves 2Mx4N, wave 128x64, acc[8][4].
// A staged as FP32 via async16 (no cvt pass!), converted to bf16 in-register after
// ds_read with v_cvt_pk_bf16_f32. 3 buffers x (A 32KB + B 16KB) = 144KB, 1 blk/CU.
// 2 phases/kt x 32 kt = 64 phases of 16 MFMA. P1 stages A(kt+2) [4 gll], P2 stages
// B(kt+2) [2 gll] + vmcnt(6) counted gate (kt+1 resident, kt+2 in flight).
// mode 0: elu+1, bf16 out, normal layout        -- LDS-staged coalesced stores
// mode 1: elu+1, bf16 out, transposed [n*1024+col][4096]
// mode 2: plain, bf16 out, transposed
__device__ __forceinline__ void gemm_f32a(const float* __restrict__ A,
                                          const unsigned short* __restrict__ B,
                                          const float* __restrict__ bias,
                                          void* __restrict__ out,
                                          int mode, char* lds, int bid) {
    const int tid = threadIdx.x;             // 0..511
    const int lane = tid & 63, wid = tid >> 6;
    const int wr = wid >> 2, wc = wid & 3;   // wave out: rows wr*128, cols wc*64
    const int lr = lane & 15, lg = lane >> 4;

    const int swz = (bid & 7) * 32 + (bid >> 3);
    const int bm = swz >> 2, bn = swz & 3;
    const long row0 = (long)bm * 256;
    const long col0 = (long)bn * 256;

    // ---- staging sources (pre-swizzled; LDS dest linear) ----
    const float* srcA[4];
#pragma unroll
    for (int g = 0; g < 4; ++g) {
        int s = g * 512 + tid;
        int pr = s >> 3;
        int dc = (s & 7) ^ (pr & 7);
        srcA[g] = A + (row0 + pr) * 1024 + dc * 4;
    }
    const unsigned short* srcB[2];
#pragma unroll
    for (int g = 0; g < 2; ++g) {
        int s = g * 512 + tid;
        int pr = s >> 3;
        int dc = (s & 7) ^ (pr & 7);
        srcB[g] = B + (col0 + pr + 128 * (dc >> 2)) * 1024 + (dc & 3) * 8;
    }
    const int dst = tid * 16;

#define STAGE_A(BUF, KT) do {                                                   \
        async16(srcA[0] + (KT) * 32, (BUF) + dst);                              \
        async16(srcA[1] + (KT) * 32, (BUF) + 8192 + dst);                       \
        async16(srcA[2] + (KT) * 32, (BUF) + 16384 + dst);                      \
        async16(srcA[3] + (KT) * 32, (BUF) + 24576 + dst); } while (0)
#define STAGE_B(BUF, KT) do {                                                   \
        async16(srcB[0] + (KT) * 32, (BUF) + 32768 + dst);                      \
        async16(srcB[1] + (KT) * 32, (BUF) + 40960 + dst); } while (0)

    int offA[8];
#pragma unroll
    for (int m = 0; m < 8; ++m)
        offA[m] = (wr * 128 + m * 16 + lr) * 128 + (((2 * lg) ^ (lr & 7)) << 4);
    int offB[4];
#pragma unroll
    for (int n = 0; n < 4; ++n)
        offB[n] = 32768 + ((wc & 1) * 64 + n * 16 + lr) * 128 +
                  ((((wc >> 1) * 4 + lg) ^ (lr & 7)) << 4);

    f32x4 acc[8][4] = {};

    char* p0 = lds;            // kt   (read)
    char* p1 = lds + 49152;    // kt+1 (landed-or-inflight)
    char* p2 = lds + 98304;    // kt+2 (stage target)

    STAGE_A(p0, 0); STAGE_B(p0, 0);
    STAGE_A(p1, 1); STAGE_B(p1, 1);
    asm volatile("s_waitcnt vmcnt(6)" ::: "memory");
    SCHED_FENCE();
    S_BARRIER();

#pragma unroll 1
    for (int kt = 0; kt < 32; ++kt) {
        short8 b[4];
        { // P1: m 0-3 ; stage A(kt+2)
            float4 a0[4], a1[4];
#pragma unroll
            for (int m = 0; m < 4; ++m) {
                a0[m] = *(const float4*)(p0 + offA[m]);
                a1[m] = *(const float4*)(p0 + (offA[m] ^ 16));
            }
#pragma unroll
            for (int n = 0; n < 4; ++n) b[n] = *(const short8*)(p0 + offB[n]);
            SCHED_FENCE();
            if (kt < 30) STAGE_A(p2, kt + 2);
            asm volatile("s_waitcnt lgkmcnt(0)" ::: "memory");
            SCHED_FENCE();
            short8 af[4];
#pragma unroll
            for (int m = 0; m < 4; ++m) {
                union { unsigned int u[4]; short8 s; } cv;
                cv.u[0] = cvtpk(a0[m].x, a0[m].y);
                cv.u[1] = cvtpk(a0[m].z, a0[m].w);
                cv.u[2] = cvtpk(a1[m].x, a1[m].y);
                cv.u[3] = cvtpk(a1[m].z, a1[m].w);
                af[m] = cv.s;
            }
            __builtin_amdgcn_s_setprio(1);
#pragma unroll
            for (int m = 0; m < 4; ++m)
#pragma unroll
                for (int n = 0; n < 4; ++n)
                    acc[m][n] = MFMA16(af[m], b[n], acc[m][n]);
            __builtin_amdgcn_s_setprio(0);
            SCHED_FENCE();
            S_BARRIER();
        }
        { // P2: m 4-7 ; stage B(kt+2) ; gate
            float4 a0[4], a1[4];
#pragma unroll
            for (int m = 0; m < 4; ++m) {
                a0[m] = *(const float4*)(p0 + offA[4 + m]);
                a1[m] = *(const float4*)(p0 + (offA[4 + m] ^ 16));
            }
            SCHED_FENCE();
            if (kt < 30) STAGE_B(p2, kt + 2);
            if (kt < 30) {
                asm volatile("s_waitcnt vmcnt(6)" ::: "memory");  // kt+1 resident
            } else {
                asm volatile("s_waitcnt vmcnt(0)" ::: "memory");  // tail (loads old)
            }
            SCHED_FENCE();
            asm volatile("s_waitcnt lgkmcnt(0)" ::: "memory");
            SCHED_FENCE();
            short8 af[4];
#pragma unroll
            for (int m = 0; m < 4; ++m) {
                union { unsigned int u[4]; short8 s; } cv;
                cv.u[0] = cvtpk(a0[m].x, a0[m].y);
                cv.u[1] = cvtpk(a0[m].z, a0[m].w);
                cv.u[2] = cvtpk(a1[m].x, a1[m].y);
                cv.u[3] = cvtpk(a1[m].z, a1[m].w);
                af[m] = cv.s;
            }
            __builtin_amdgcn_s_setprio(1);
#pragma unroll
            for (int m = 0; m < 4; ++m)
#pragma unroll
                for (int n = 0; n < 4; ++n)
                    acc[4 + m][n] = MFMA16(af[m], b[n], acc[4 + m][n]);
            __builtin_amdgcn_s_setprio(0);
            SCHED_FENCE();
            S_BARRIER();
        }
        char* t_ = p0; p0 = p1; p1 = p2; p2 = t_;
    }
#undef STAGE_A
#undef STAGE_B

    // ---- epilogue ----
    const int r4 = lg * 4;
    if (mode == 0) {
        char* ep = lds + wid * 4608;
#pragma unroll
        for (int m = 0; m < 8; ++m) {
#pragma unroll
            for (int n = 0; n < 4; ++n) {
                float bcol = bias[col0 + wc * 64 + n * 16 + lr];
#pragma unroll
                for (int j = 0; j < 4; ++j) {
                    float v = acc[m][n][j] + bcol;
                    v = v > 0.f ? v + 1.f : __expf(v);
                    *(float*)(ep + (((lg * 4 + j) * 68) + n * 16 + lr) * 4) = v;
                }
            }
            asm volatile("s_waitcnt lgkmcnt(0)" ::: "memory");
            SCHED_FENCE();
            long R0b = row0 + wr * 128 + m * 16;
            unsigned short* O = (unsigned short*)out;
#pragma unroll
            for (int i = 0; i < 2; ++i) {
                int r = i * 8 + (lane >> 3), c8 = (lane & 7) * 8;
                float4 u0 = *(const float4*)(ep + (r * 68 + c8) * 4);
                float4 u1 = *(const float4*)(ep + (r * 68 + c8 + 4) * 4);
                uint4 w;
                w.x = pk2(u0.x, u0.y); w.y = pk2(u0.z, u0.w);
                w.z = pk2(u1.x, u1.y); w.w = pk2(u1.z, u1.w);
                *(uint4*)(O + (R0b + r) * 1024 + col0 + wc * 64 + c8) = w;
            }
            asm volatile("s_waitcnt lgkmcnt(0)" ::: "memory");
            SCHED_FENCE();
        }
    } else {
#pragma unroll
        for (int m = 0; m < 8; ++m) {
#pragma unroll
            for (int n = 0; n < 4; ++n) {
                long col = col0 + wc * 64 + n * 16 + lr;
                float bcol = bias[col];
                long R0 = row0 + wr * 128 + m * 16 + r4;
                unsigned short* O = (unsigned short*)out;
                long nb = R0 >> 12;
                long s = R0 & 4095;
                short4v pack;
#pragma unroll
                for (int j = 0; j < 4; ++j) {
                    float v = acc[m][n][j] + bcol;
                    if (mode == 1) v = v > 0.f ? v + 1.f : __expf(v);
                    pack[j] = (short)f2bf(v);
                }
                *(short4v*)(O + ((nb << 10) + col) * 4096 + s) = pack;
            }
        }
    }
}

// ========== bf16 GEMM body (R9-verified, for output projection) ==========
__device__ __forceinline__ void gemm_body(const unsigned short* __restrict__ A,
                                          const unsigned short* __restrict__ B,
                                          const float* __restrict__ bias,
                                          float* __restrict__ out,
                                          char* lds, int bid) {
    const int tid = threadIdx.x;
    const int lane = tid & 63, wid = tid >> 6;
    const int wr = wid >> 2, wc = wid & 3;
    const int lr = lane & 15, lg = lane >> 4;

    const int swz = (bid & 7) * 32 + (bid >> 3);
    const int bm = swz >> 2, bn = swz & 3;
    const long row0 = (long)bm * 256;
    const long col0 = (long)bn * 256;

    const unsigned short* srcA[2];
    const unsigned short* srcB[2];
    int dstOff[2];
#pragma unroll
    for (int g = 0; g < 2; ++g) {
        int s = g * 512 + tid;
        int pr = s >> 3;
        int dc = (s & 7) ^ (pr & 7);
        srcA[g] = A + (row0 + (pr & 63) + 128 * (pr >> 6)) * 1024 + dc * 8;
        srcB[g] = B + (col0 + pr) * 1024 + dc * 8;
        dstOff[g] = s * 16;
    }

#define STG_AQ(BB, Q, KT) do {                                                  \
        async16(srcA[0] + (Q) * 65536 + (KT) * 64,                              \
                lds + (BB) * 65536 + (Q) * 16384 + dstOff[0]);                  \
        async16(srcA[1] + (Q) * 65536 + (KT) * 64,                              \
                lds + (BB) * 65536 + (Q) * 16384 + dstOff[1]); } while (0)
#define STG_BH(BB, H, KT) do {                                                  \
        async16(srcB[0] + (H) * 131072 + (KT) * 64,                             \
                lds + (BB) * 65536 + 32768 + (H) * 16384 + dstOff[0]);          \
        async16(srcB[1] + (H) * 131072 + (KT) * 64,                             \
                lds + (BB) * 65536 + 32768 + (H) * 16384 + dstOff[1]); } while (0)

    const int ch0 = ((lg ^ (lr & 7)) << 4);
    const int ch1 = (((4 + lg) ^ (lr & 7)) << 4);
    const int aB0 = (64 * wr + lr) * 128 + ch0;
    const int aB1 = (64 * wr + lr) * 128 + ch1;
    const int bB0 = 32768 + (wc >> 1) * 16384 + ((wc & 1) * 64 + lr) * 128 + ch0;
    const int bB1 = 32768 + (wc >> 1) * 16384 + ((wc & 1) * 64 + lr) * 128 + ch1;

    f32x4 acc[8][4] = {};
    short8 b0[4], b1[4];

#define GATE4() do { asm volatile("s_waitcnt vmcnt(4)" ::: "memory"); SCHED_FENCE(); } while (0)
#define GATE0() do { asm volatile("s_waitcnt vmcnt(0)" ::: "memory"); SCHED_FENCE(); } while (0)
#define MFMA_BLOCK(MB, BV) do {                                                 \
        S_BARRIER();                                                            \
        asm volatile("s_waitcnt lgkmcnt(0)" ::: "memory");                      \
        SCHED_FENCE();                                                          \
        __builtin_amdgcn_s_setprio(1);                                          \
        _Pragma("unroll") for (int m = 0; m < 4; ++m)                           \
            _Pragma("unroll") for (int n = 0; n < 4; ++n)                       \
                acc[(MB) + m][n] = MFMA16(a[m], BV[n], acc[(MB) + m][n]);       \
        __builtin_amdgcn_s_setprio(0);                                          \
        SCHED_FENCE();                                                          \
        S_BARRIER(); } while (0)
#define LOAD_A(BUFB, ABASE, Q) do {                                             \
        _Pragma("unroll") for (int m = 0; m < 4; ++m)                           \
            a[m] = *(const short8*)(lds + (BUFB) + (Q) * 16384 + (ABASE) + m * 2048); } while (0)
#define LOAD_B(BUFB, BBASE, BV) do {                                            \
        _Pragma("unroll") for (int n = 0; n < 4; ++n)                           \
            BV[n] = *(const short8*)(lds + (BUFB) + (BBASE) + n * 2048); } while (0)

    STG_AQ(0, 0, 0); STG_BH(0, 0, 0); STG_BH(0, 1, 0); STG_AQ(0, 1, 0);
    STG_AQ(1, 0, 1); STG_BH(1, 0, 1);
    GATE4();
    S_BARRIER();

#pragma unroll 1
    for (int t = 0; t < 7; ++t) {
        const int ktA = 2 * t + 1, ktB = 2 * t + 2, ktC = 2 * t + 3;
        { short8 a[4]; LOAD_B(0, bB0, b0); LOAD_A(0, aB0, 0); STG_BH(1, 1, ktA); MFMA_BLOCK(0, b0); }
        { short8 a[4]; LOAD_B(0, bB1, b1); LOAD_A(0, aB1, 0); STG_AQ(1, 1, ktA); MFMA_BLOCK(0, b1); }
        { short8 a[4]; LOAD_A(0, aB0, 1); STG_AQ(0, 0, ktB); MFMA_BLOCK(4, b0); }
        { short8 a[4]; LOAD_A(0, aB1, 1); STG_BH(0, 0, ktB); GATE4(); MFMA_BLOCK(4, b1); }
        { short8 a[4]; LOAD_B(65536, bB0, b0); LOAD_A(65536, aB0, 0); STG_BH(0, 1, ktB); MFMA_BLOCK(0, b0); }
        { short8 a[4]; LOAD_B(65536, bB1, b1); LOAD_A(65536, aB1, 0); STG_AQ(0, 1, ktB); MFMA_BLOCK(0, b1); }
        { short8 a[4]; LOAD_A(65536, aB0, 1); STG_AQ(1, 0, ktC); MFMA_BLOCK(4, b0); }
        { short8 a[4]; LOAD_A(65536, aB1, 1); STG_BH(1, 0, ktC); GATE4(); MFMA_BLOCK(4, b1); }
    }
    {
        { short8 a[4]; LOAD_B(0, bB0, b0); LOAD_A(0, aB0, 0); STG_BH(1, 1, 15); MFMA_BLOCK(0, b0); }
        { short8 a[4]; LOAD_B(0, bB1, b1); LOAD_A(0, aB1, 0); STG_AQ(1, 1, 15); MFMA_BLOCK(0, b1); }
        { short8 a[4]; LOAD_A(0, aB0, 1); MFMA_BLOCK(4, b0); }
        { short8 a[4]; LOAD_A(0, aB1, 1); GATE0(); MFMA_BLOCK(4, b1); }
        { short8 a[4]; LOAD_B(65536, bB0, b0); LOAD_A(65536, aB0, 0); MFMA_BLOCK(0, b0); }
        { short8 a[4]; LOAD_B(65536, bB1, b1); LOAD_A(65536, aB1, 0); MFMA_BLOCK(0, b1); }
        { short8 a[4]; LOAD_A(65536, aB0, 1); MFMA_BLOCK(4, b0); }
        { short8 a[4]; LOAD_A(65536, aB1, 1); MFMA_BLOCK(4, b1); }
    }
#undef STG_AQ
#undef STG_BH
#undef GATE4
#undef GATE0
#undef MFMA_BLOCK
#undef LOAD_A
#undef LOAD_B

    {
        char* ep = lds + wid * 4608;
#pragma unroll
        for (int m = 0; m < 8; ++m) {
#pragma unroll
            for (int n = 0; n < 4; ++n) {
                float bcol = bias[col0 + wc * 64 + n * 16 + lr];
#pragma unroll
                for (int j = 0; j < 4; ++j)
                    *(float*)(ep + (((lg * 4 + j) * 68) + n * 16 + lr) * 4) = acc[m][n][j] + bcol;
            }
            asm volatile("s_waitcnt lgkmcnt(0)" ::: "memory");
            SCHED_FENCE();
            long R0b = row0 + wr * 128 + m * 16;
#pragma unroll
            for (int i = 0; i < 4; ++i) {
                int r = i * 4 + (lane >> 4), c4 = (lane & 15) * 4;
                float4 u = *(const float4*)(ep + (r * 68 + c4) * 4);
                *(float4*)(out + (R0b + r) * 1024 + col0 + wc * 64 + c4) = u;
            }
            asm volatile("s_waitcnt lgkmcnt(0)" ::: "memory");
            SCHED_FENCE();
        }
    }
}

// ---- merged Q/K/V projection from FP32 inputs: 768 blocks ----
__global__ __launch_bounds__(512, 1) void proj_gemm(const float* __restrict__ q,
                                                    const float* __restrict__ k,
                                                    const float* __restrict__ v,
                                                    const unsigned short* __restrict__ Wqb,
                                                    const unsigned short* __restrict__ Wkb,
                                                    const unsigned short* __restrict__ Wvb,
                                                    const float* __restrict__ bq,
                                                    const float* __restrict__ bk,
                                                    const float* __restrict__ bv,
                                                    unsigned short* __restrict__ Qm,
                                                    unsigned short* __restrict__ Kt,
                                                    unsigned short* __restrict__ vT) {
    __shared__ __align__(16) char lds[147456];
    int seg = blockIdx.x >> 8;
    int bid = blockIdx.x & 255;
    const float* A = seg == 0 ? q : seg == 1 ? k : v;
    const unsigned short* B = seg == 0 ? Wqb : seg == 1 ? Wkb : Wvb;
    const float* bias = seg == 0 ? bq : seg == 1 ? bk : bv;
    void* out = seg == 0 ? (void*)Qm : seg == 1 ? (void*)Kt : (void*)vT;
    gemm_f32a(A, B, bias, out, seg, lds, bid);   // mode 0/1/2 == seg
}

// ---- output projection: 256 blocks, bf16 A (R9 body) ----
__global__ __launch_bounds__(512, 1) void out_gemm(const unsigned short* __restrict__ Vbuf,
                                                   const unsigned short* __restrict__ Wob,
                                                   const float* __restrict__ bo,
                                                   float* __restrict__ out) {
    __shared__ __align__(16) char lds[131072];
    gemm_body(Vbuf, Wob, bo, out, lds, blockIdx.x);
}

// ---------------- KV[n,h,m,d] = sum_s vT[...][s] * Kt[...][s]; Ksum fused from B-frags ----
__global__ __launch_bounds__(256) void kv_kernel(const unsigned short* __restrict__ Kt,
                                                 const unsigned short* __restrict__ vT,
                                                 float* __restrict__ KV,
                                                 float* __restrict__ Ksum) {
    int b = blockIdx.x;
    int sc = b & 7, h = (b >> 3) & 15, n = b >> 7;
    const int tid = threadIdx.x, lane = tid & 63, wave = tid >> 6;
    long base = ((long)(n * 1024 + h * 64)) * 4096 + sc * 512;
    const unsigned short* Kp = Kt + base;
    const unsigned short* Vp = vT + base;
    const int lr = lane & 15, lk = (lane >> 4) * 8;

    f32x4 acc[4] = {};
    float ksa[4] = {0.f, 0.f, 0.f, 0.f};
    for (int s0 = 0; s0 < 512; s0 += 32) {
        short8 a = *(const short8*)(Vp + (long)(wave * 16 + lr) * 4096 + s0 + lk);
#pragma unroll
        for (int d4 = 0; d4 < 4; ++d4) {
            short8 bb = *(const short8*)(Kp + (long)(d4 * 16 + lr) * 4096 + s0 + lk);
            acc[d4] = MFMA16(a, bb, acc[d4]);
            if (wave == 0) {
                float t = 0.f;
#pragma unroll
                for (int e = 0; e < 8; ++e) t += bf2f((unsigned short)bb[e]);
                ksa[d4] += t;
            }
        }
    }
    float* KVb = KV + (long)(n * 16 + h) * 4096;
#pragma unroll
    for (int d4 = 0; d4 < 4; ++d4)
#pragma unroll
        for (int j = 0; j < 4; ++j) {
            int m = wave * 16 + (lane >> 4) * 4 + j;
            int d = d4 * 16 + lr;
            atomicAdd(KVb + m * 64 + d, acc[d4][j]);
        }
    if (wave == 0) {
#pragma unroll
        for (int d4 = 0; d4 < 4; ++d4) {
            float t = ksa[d4];
            t += __shfl_xor(t, 16, 64);
            t += __shfl_xor(t, 32, 64);
            if (lane < 16) atomicAdd(Ksum + n * 1024 + h * 64 + d4 * 16 + lane, t);
        }
    }
}

// ---------------- attn: V[n,l,h,m] = (sum_d Q[l,d]*KV[m,d]) / (Q[l,:]·Ksum + eps) ----------------
__global__ __launch_bounds__(256) void attn_kernel(const unsigned short* __restrict__ Qm,
                                                   const float* __restrict__ KV,
                                                   const float* __restrict__ Ksum,
                                                   unsigned short* __restrict__ Vbuf) {
    __shared__ unsigned short Qs[128 * 64];
    __shared__ unsigned short KVs[64 * 64];
    __shared__ float zin[128];
    __shared__ float ks[64];
    int b = blockIdx.x;
    int lc = b & 31, h = (b >> 5) & 15, n = b >> 9;
    int tid = threadIdx.x, lane = tid & 63, wave = tid >> 6;
    long l0 = (long)n * 4096 + lc * 128;

    const unsigned short* Qg = Qm + (l0 + (tid >> 3)) * 1024 + h * 64 + (tid & 7) * 8;
    char* QsB = (char*)Qs + (wave << 10);
#pragma unroll
    for (int it = 0; it < 4; ++it)
        async16(Qg + (long)it * 32 * 1024, QsB + it * 4096);

    const float* kvp = KV + (long)(n * 16 + h) * 4096;
    for (int i = tid * 4; i < 4096; i += 1024) {
        float4 v = *reinterpret_cast<const float4*>(kvp + i);
        short4v p;
        p[0] = (short)f2bf(v.x); p[1] = (short)f2bf(v.y);
        p[2] = (short)f2bf(v.z); p[3] = (short)f2bf(v.w);
        *(short4v*)(KVs + i) = p;
    }
    if (tid < 64) ks[tid] = Ksum[n * 1024 + h * 64 + tid];
    __syncthreads();

    {
        int row = tid >> 1, half = tid & 1;
        float den = 0.f;
        const unsigned short* qrow = Qs + row * 64 + half * 32;
#pragma unroll
        for (int d = 0; d < 32; ++d) den += bf2f(qrow[d]) * ks[half * 32 + d];
        den += __shfl_xor(den, 1, 64);
        if (half == 0) zin[row] = 1.0f / (den + 1e-6f);
    }
    __syncthreads();

    const int lr = lane & 15, lk = (lane >> 4) * 8;
    f32x4 acc[2][4] = {};
#pragma unroll
    for (int kk = 0; kk < 2; ++kk) {
        short8 a0 = *(const short8*)(Qs + (wave * 32 + lr) * 64 + kk * 32 + lk);
        short8 a1 = *(const short8*)(Qs + (wave * 32 + 16 + lr) * 64 + kk * 32 + lk);
#pragma unroll
        for (int nn = 0; nn < 4; ++nn) {
            short8 bb = *(const short8*)(KVs + (nn * 16 + lr) * 64 + kk * 32 + lk);
            acc[0][nn] = MFMA16(a0, bb, acc[0][nn]);
            acc[1][nn] = MFMA16(a1, bb, acc[1][nn]);
        }
    }

    {
        char* ep = (char*)Qs + wave * 4096;
#pragma unroll
        for (int mi = 0; mi < 2; ++mi) {
#pragma unroll
            for (int nn = 0; nn < 4; ++nn)
#pragma unroll
                for (int j = 0; j < 4; ++j) {
                    int rloc = (lane >> 4) * 4 + j;
                    float v = acc[mi][nn][j] * zin[wave * 32 + mi * 16 + rloc];
                    *(float*)(ep + (rloc * 64 + nn * 16 + lr) * 4) = v;
                }
            asm volatile("s_waitcnt lgkmcnt(0)" ::: "memory");
            SCHED_FENCE();
#pragma unroll
            for (int i = 0; i < 2; ++i) {
                int r = i * 8 + (lane >> 3), c8 = (lane & 7) * 8;
                float4 u0 = *(const float4*)(ep + (r * 64 + c8) * 4);
                float4 u1 = *(const float4*)(ep + (r * 64 + c8 + 4) * 4);
                uint4 w;
                w.x = pk2(u0.x, u0.y); w.y = pk2(u0.z, u0.w);
                w.z = pk2(u1.x, u1.y); w.w = pk2(u1.z, u1.w);
                *(uint4*)(Vbuf + (l0 + wave * 32 + mi * 16 + r) * 1024 + h * 64 + c8) = w;
            }
            asm volatile("s_waitcnt lgkmcnt(0)" ::: "memory");
            SCHED_FENCE();
        }
    }
}

extern "C" void kernel_launch(void* const* d_in, const int* in_sizes, int n_in,
                              void* d_out, int out_size, void* d_ws, size_t ws_size,
                              hipStream_t stream) {
    const float* queries = (const float*)d_in[0];
    const float* keys    = (const float*)d_in[1];
    const float* values  = (const float*)d_in[2];
    const float* Wq = (const float*)d_in[3];
    const float* bq = (const float*)d_in[4];
    const float* Wk = (const float*)d_in[5];
    const float* bk = (const float*)d_in[6];
    const float* Wv = (const float*)d_in[7];
    const float* bv = (const float*)d_in[8];
    const float* Wo = (const float*)d_in[9];
    const float* bo = (const float*)d_in[10];
    float* out = (float*)d_out;

    char* ws = (char*)d_ws;
    const size_t SZ = (size_t)16384 * 1024 * 2;  // 33.5 MB bf16 matrix
    const size_t WSZ = (size_t)1024 * 1024 * 2;  // 2 MB bf16 weight
    unsigned short* Wqb = (unsigned short*)(ws);
    unsigned short* Wkb = (unsigned short*)(ws + WSZ);
    unsigned short* Wvb = (unsigned short*)(ws + 2 * WSZ);
    unsigned short* Wob = (unsigned short*)(ws + 3 * WSZ);
    unsigned short* Qm   = (unsigned short*)(ws + 4 * WSZ);
    unsigned short* Kt   = (unsigned short*)(ws + 4 * WSZ + SZ);
    unsigned short* vT   = (unsigned short*)(ws + 4 * WSZ + 2 * SZ);
    unsigned short* Vbuf = (unsigned short*)(ws + 4 * WSZ + 3 * SZ);
    float* KVf = (float*)(ws + 4 * WSZ + 4 * SZ);
    float* Ksf = (float*)(ws + 4 * WSZ + 4 * SZ + 1048576);

    hipMemsetAsync(KVf, 0, 1048576 + 16384, stream);

    cvt4_kernel<<<512, 256, 0, stream>>>(Wq, Wk, Wv, Wo, Wqb, Wkb, Wvb, Wob);

    proj_gemm<<<768, 512, 0, stream>>>(queries, keys, values, Wqb, Wkb, Wvb,
                                       bq, bk, bv, Qm, Kt, vT);

    kv_kernel<<<512, 256, 0, stream>>>(Kt, vT, KVf, Ksf);
    attn_kernel<<<2048, 256, 0, stream>>>(Qm, KVf, Ksf, Vbuf);

    out_gemm<<<256, 512, 0, stream>>>(Vbuf, Wob, bo, out);
}